// Round 6
// baseline (216.656 us; speedup 1.0000x reference)
//
#include <hip/hip_runtime.h>

typedef _Float16 f16;
typedef __attribute__((ext_vector_type(8))) _Float16 f16x8;
typedef __attribute__((ext_vector_type(4))) float f32x4;

#define ND 256
#define OD 256

// ws layout: rs int[ng+1] | pad to 256B | W2 f16[32][256][8] (128 KB)

__global__ void k_rowstarts(const int* __restrict__ b32, int N, int ng, int* __restrict__ rs) {
    __shared__ int s_is64;
    if (threadIdx.x == 0) {
        // Sniff dtype: int64 batch has zero high words.
        int m = (N / 2) & ~1;
        bool oz = true;
        for (int j = 0; j < 8; ++j) oz &= (b32[m + 2*j + 1] == 0);
        s_is64 = oz ? 1 : 0;
    }
    __syncthreads();
    const bool is64 = (s_is64 != 0);
    int g = blockIdx.x * blockDim.x + threadIdx.x;
    if (g > ng) return;
    int lo = 0, hi = N;
    while (lo < hi) {
        int mid = (lo + hi) >> 1;
        int v = is64 ? b32[2*mid] : b32[mid];
        if (v < g) lo = mid + 1; else hi = mid;
    }
    rs[g] = lo;
}

// Repack value_w [k][j] -> W2 [k/8][j][k%8] as f16 (B-frag = 16 contiguous bytes).
__global__ void k_wpack(const float* __restrict__ W, f16* __restrict__ W2) {
    const int kb = blockIdx.x;      // 0..31
    const int j  = threadIdx.x;     // 0..255
    f16x8 v;
    #pragma unroll
    for (int e = 0; e < 8; ++e)
        v[e] = (f16)W[(size_t)(kb * 8 + e) * OD + j];
    *(f16x8*)(W2 + (size_t)kb * 2048 + j * 8) = v;
}

// Issue one 16-row chunk of x into a named register bank (plain arrays,
// compile-time indices after unroll: stays in VGPRs; no address capture).
#define ISSUE_CHUNK(RA, RB, ROW)                                             \
    {                                                                        \
        const int r_ = (ROW);                                                \
        const bool v_ = r_ < segN;                                           \
        const float* xp_ = x + (size_t)(seg0 + r_) * ND + h * 8;             \
        _Pragma("unroll")                                                    \
        for (int ks = 0; ks < 8; ++ks) {                                     \
            if (v_) {                                                        \
                RA[ks] = *(const float4*)(xp_ + ks * 32);                    \
                RB[ks] = *(const float4*)(xp_ + ks * 32 + 4);                \
            } else {                                                         \
                RA[ks] = f4z; RB[ks] = f4z;                                  \
            }                                                                \
        }                                                                    \
    }

// Consume a bank: gate partial dot (f32) + convert to f16 A-fragments.
#define CONSUME_CHUNK(RA, RB, AV, GP)                                        \
    {                                                                        \
        float g1_ = 0.f, g2_ = 0.f;                                          \
        _Pragma("unroll")                                                    \
        for (int ks = 0; ks < 8; ++ks) {                                     \
            const float4 a = RA[ks], b = RB[ks];                             \
            const float4 wa = *(const float4*)(gwl + ks * 32 + h * 8);       \
            const float4 wb = *(const float4*)(gwl + ks * 32 + h * 8 + 4);   \
            g1_ += (a.x*wa.x + a.y*wa.y) + (a.z*wa.z + a.w*wa.w);            \
            g2_ += (b.x*wb.x + b.y*wb.y) + (b.z*wb.z + b.w*wb.w);            \
            AV[ks][0] = (f16)a.x; AV[ks][1] = (f16)a.y;                      \
            AV[ks][2] = (f16)a.z; AV[ks][3] = (f16)a.w;                      \
            AV[ks][4] = (f16)b.x; AV[ks][5] = (f16)b.y;                      \
            AV[ks][6] = (f16)b.z; AV[ks][7] = (f16)b.w;                      \
        }                                                                    \
        GP = g1_ + g2_;                                                      \
    }

// 1024 threads = 16 waves = 4 waves/SIMD (2x the old occupancy). The 1024
// flat-work-group-size forces the allocator to <=128 VGPR/wave, so the body
// is kept lean: single 64-reg load bank, cs-loop unroll 1, no per-wave
// software pipeline (4-wave TLP does the latency hiding instead).
__global__ __launch_bounds__(1024, 4)
void k_main(const float* __restrict__ x, const int* __restrict__ rs,
            const float* __restrict__ gate_w, const float* __restrict__ gate_b,
            const f16* __restrict__ W2, const float* __restrict__ value_b,
            float* __restrict__ zout, float* __restrict__ attn, int ng) {
    __shared__ __align__(16) f16 Bl[32 * 256 * 8];   // 128 KB, [kb][col][8]
    __shared__ float gwl[ND];
    __shared__ float vbl[OD];

    const int tid = threadIdx.x;    // 0..1023
    const int wid = tid >> 6;       // 0..15
    const int lane = tid & 63;
    const int rowl = lane & 15;
    const int h = lane >> 4;

    // one-time: B -> LDS (coalesced linear), gate_w / value_b -> LDS
    #pragma unroll
    for (int i = 0; i < 8; ++i) {
        const int f = i * 1024 + tid;
        *(f16x8*)((char*)Bl + (size_t)f * 16) = *(const f16x8*)(W2 + (size_t)f * 8);
    }
    if (tid < ND) gwl[tid] = gate_w[tid];
    else if (tid < ND + OD) vbl[tid - ND] = value_b[tid - ND];
    __syncthreads();   // ONLY block barrier

    const float gb = gate_b[0];
    const float4 f4z = make_float4(0.f, 0.f, 0.f, 0.f);

    const int g = blockIdx.x * 16 + wid;   // one graph per wave
    if (g >= ng) return;
    const int seg0 = rs[g], seg1 = rs[g + 1];
    const int segN = seg1 - seg0;

    float S = 0.f;                                  // per-lane partial (h==0 masked)
    float zs[16];
    #pragma unroll
    for (int cs = 0; cs < 16; ++cs) zs[cs] = 0.f;

    const int nt = (segN + 15) >> 4;   // 16-row tiles

    #pragma unroll 1
    for (int t = 0; t < nt; ++t) {
        const int row = t * 16 + rowl;
        const bool vr = row < segN;

        float4 ra[8], rb[8];
        ISSUE_CHUNK(ra, rb, row);

        float gp;
        f16x8 av[8];
        CONSUME_CHUNK(ra, rb, av, gp);

        gp += __shfl_xor(gp, 16, 64);
        gp += __shfl_xor(gp, 32, 64);
        const float wv = vr ? __expf(fminf(gp + gb, 60.f)) : 0.f;
        if (h == 0 && vr) attn[seg0 + row] = wv;    // stash exp(g)
        S += (h == 0) ? wv : 0.f;                   // deferred reduction

        const float w0 = __shfl(wv, h * 4 + 0, 64);
        const float w1 = __shfl(wv, h * 4 + 1, 64);
        const float w2 = __shfl(wv, h * 4 + 2, 64);
        const float w3 = __shfl(wv, h * 4 + 3, 64);

        // 16 col-slices: 8 B-frag reads + 8 MFMA each (unroll 1: low pressure)
        #pragma unroll 1
        for (int cs = 0; cs < 16; ++cs) {
            f32x4 ac = {0.f, 0.f, 0.f, 0.f};
            const char* bb = (const char*)Bl + h * 4096 + (size_t)(cs * 16 + rowl) * 16;
            #pragma unroll
            for (int ks = 0; ks < 8; ++ks) {
                const f16x8 bf = *(const f16x8*)(bb + ks * 16384);
                ac = __builtin_amdgcn_mfma_f32_16x16x32_f16(av[ks], bf, ac, 0, 0, 0);
            }
            const float vbv = vbl[cs * 16 + rowl];
            float p0 = ac[0] + vbv, p1 = ac[1] + vbv;
            float p2 = ac[2] + vbv, p3 = ac[3] + vbv;
            zs[cs] += w0 * p0 * __builtin_amdgcn_rcpf(1.f + __expf(-p0))
                    + w1 * p1 * __builtin_amdgcn_rcpf(1.f + __expf(-p1))
                    + w2 * p2 * __builtin_amdgcn_rcpf(1.f + __expf(-p2))
                    + w3 * p3 * __builtin_amdgcn_rcpf(1.f + __expf(-p3));
        }
    }

    // graph end: single S butterfly (h!=0 lanes hold 0 partials)
    #pragma unroll
    for (int off = 32; off >= 1; off >>= 1) S += __shfl_xor(S, off, 64);

    const float inv = __builtin_amdgcn_rcpf(S + 1e-8f);
    #pragma unroll
    for (int cs = 0; cs < 16; ++cs) {
        float v = zs[cs];
        v += __shfl_xor(v, 16, 64);
        v += __shfl_xor(v, 32, 64);
        if (lane < 16) zout[(size_t)g * OD + cs * 16 + lane] = v * inv;
    }
    asm volatile("s_waitcnt vmcnt(0)" ::: "memory");   // exp(g) stores visible
    for (int i = seg0 + lane; i < seg1; i += 64)
        attn[i] = attn[i] * inv;                        // pure scale
}

extern "C" void kernel_launch(void* const* d_in, const int* in_sizes, int n_in,
                              void* d_out, int out_size, void* d_ws, size_t ws_size,
                              hipStream_t stream) {
    const float* x       = (const float*)d_in[0];
    const int*   batch   = (const int*)d_in[1];
    const float* gate_w  = (const float*)d_in[3];
    const float* gate_b  = (const float*)d_in[4];
    const float* value_w = (const float*)d_in[5];
    const float* value_b = (const float*)d_in[6];

    const int N  = in_sizes[1];
    const int ng = (out_size - N) / OD;

    int* rs = (int*)d_ws;
    f16* W2 = (f16*)(((uintptr_t)(rs + ng + 1) + 255) & ~(uintptr_t)255);

    k_rowstarts<<<(ng + 1 + 255) / 256, 256, 0, stream>>>(batch, N, ng, rs);
    k_wpack<<<32, 256, 0, stream>>>(value_w, W2);

    float* zout = (float*)d_out;
    float* attn = zout + (size_t)ng * OD;

    k_main<<<(ng + 15) / 16, 1024, 0, stream>>>(x, rs, gate_w, gate_b, W2, value_b,
                                                zout, attn, ng);
}

// Round 7
// 176.408 us; speedup vs baseline: 1.2282x; 1.2282x over previous
//
#include <hip/hip_runtime.h>

typedef _Float16 f16;
typedef __attribute__((ext_vector_type(8))) _Float16 f16x8;
typedef __attribute__((ext_vector_type(4))) float f32x4;

#define ND 256
#define OD 256

// ws layout: rs int[ng+1] | pad to 256B | W2 f16[32][256][8] (128 KB)

__global__ void k_rowstarts(const int* __restrict__ b32, int N, int ng, int* __restrict__ rs) {
    __shared__ int s_is64;
    if (threadIdx.x == 0) {
        // Sniff dtype: int64 batch has zero high words.
        int m = (N / 2) & ~1;
        bool oz = true;
        for (int j = 0; j < 8; ++j) oz &= (b32[m + 2*j + 1] == 0);
        s_is64 = oz ? 1 : 0;
    }
    __syncthreads();
    const bool is64 = (s_is64 != 0);
    int g = blockIdx.x * blockDim.x + threadIdx.x;
    if (g > ng) return;
    int lo = 0, hi = N;
    while (lo < hi) {
        int mid = (lo + hi) >> 1;
        int v = is64 ? b32[2*mid] : b32[mid];
        if (v < g) lo = mid + 1; else hi = mid;
    }
    rs[g] = lo;
}

// Repack value_w [k][j] -> W2 [k/8][j][k%8] as f16 (B-frag = 16 contiguous bytes).
__global__ void k_wpack(const float* __restrict__ W, f16* __restrict__ W2) {
    const int kb = blockIdx.x;      // 0..31
    const int j  = threadIdx.x;     // 0..255
    f16x8 v;
    #pragma unroll
    for (int e = 0; e < 8; ++e)
        v[e] = (f16)W[(size_t)(kb * 8 + e) * OD + j];
    *(f16x8*)(W2 + (size_t)kb * 2048 + j * 8) = v;
}

// Block-per-graph design: 1024 threads = 16 waves = 8 col-groups x 2 row-groups.
// B lives in registers (64 VGPR/wave, loaded once; persistent blocks).
// x is reg-staged -> f16 LDS tile (32 rows, XOR-swizzled); gate computed during
// staging from the f32 registers. Raw s_barrier (no vmcnt drain) so next tile's
// global loads stay in flight across the barrier.
__global__ __attribute__((amdgpu_flat_work_group_size(1024, 1024)))
void k_main(const float* __restrict__ x, const int* __restrict__ rs,
            const float* __restrict__ gate_w, const float* __restrict__ gate_b,
            const f16* __restrict__ W2, const float* __restrict__ value_b,
            float* __restrict__ zout, float* __restrict__ attn, int ng) {
    __shared__ __align__(1024) f16 Xb[2][32 * 256];   // 2 x 16 KB swizzled x-tiles
    __shared__ __align__(16) float gexpL[2][32];      // per-row exp(gate), dbuf
    __shared__ __align__(16) float zred[256];         // cross-row-group z reduce
    __shared__ float sred[16];                        // per-wave S partials

    const int tid  = threadIdx.x;          // 0..1023
    const int wid  = tid >> 6;             // 0..15
    const int lane = tid & 63;
    const int rowl = lane & 15;
    const int h    = lane >> 4;
    const int cw   = wid & 7;              // col-group: cols [cw*32, cw*32+32)
    const int rw   = wid >> 3;             // row-group: rows [rw*16, rw*16+16)
    const int srow = tid >> 5;             // staging row 0..31
    const int kq   = tid & 31;             // staging k-chunk (8 floats)

    // persistent B fragments (64 VGPR): Bf[cs][ks], col = cw*32 + cs*16 + rowl
    f16x8 Bf[2][8];
    #pragma unroll
    for (int cs = 0; cs < 2; ++cs)
        #pragma unroll
        for (int ks = 0; ks < 8; ++ks)
            Bf[cs][ks] = *(const f16x8*)((const char*)W2 + (size_t)(ks * 4 + h) * 4096
                                          + (size_t)(cw * 32 + cs * 16 + rowl) * 16);
    const float4 gwa = *(const float4*)(gate_w + kq * 8);
    const float4 gwb = *(const float4*)(gate_w + kq * 8 + 4);
    const float vb0 = value_b[cw * 32 + rowl];
    const float vb1 = value_b[cw * 32 + 16 + rowl];
    const float gb  = gate_b[0];
    const float4 f4z = make_float4(0.f, 0.f, 0.f, 0.f);

    float4 xa = f4z, xb = f4z;             // staging regs (32 B / lane)

    int g = blockIdx.x;
    int seg0 = 0, segN = 0;
    if (g < ng) {
        seg0 = rs[g]; segN = rs[g + 1] - seg0;
        if (srow < segN) {                 // prefetch tile 0 of first graph
            const float* xp = x + (size_t)(seg0 + srow) * ND + kq * 8;
            xa = *(const float4*)xp; xb = *(const float4*)(xp + 4);
        } else { xa = f4z; xb = f4z; }
    }

    while (g < ng) {
        const int nt = (segN + 31) >> 5;
        float S = 0.f, z0 = 0.f, z1 = 0.f;

        #pragma unroll 1
        for (int t = 0; t < nt; ++t) {
            // ---- staging: consume regs (gate dot + f16 cvt + swizzled write)
            float gp = (xa.x*gwa.x + xa.y*gwa.y) + (xa.z*gwa.z + xa.w*gwa.w)
                     + (xb.x*gwb.x + xb.y*gwb.y) + (xb.z*gwb.z + xb.w*gwb.w);
            f16x8 xv;
            xv[0] = (f16)xa.x; xv[1] = (f16)xa.y; xv[2] = (f16)xa.z; xv[3] = (f16)xa.w;
            xv[4] = (f16)xb.x; xv[5] = (f16)xb.y; xv[6] = (f16)xb.z; xv[7] = (f16)xb.w;
            *(f16x8*)((char*)&Xb[t & 1][0] +
                      (((srow * 512) + (kq * 16)) ^ ((srow & 7) << 4))) = xv;

            // gate reduce across the 32 staging lanes of this row
            gp += __shfl_xor(gp, 1, 32);
            gp += __shfl_xor(gp, 2, 32);
            gp += __shfl_xor(gp, 4, 32);
            gp += __shfl_xor(gp, 8, 32);
            gp += __shfl_xor(gp, 16, 32);
            const int trow = t * 32 + srow;
            const float ex = (trow < segN) ? __expf(fminf(gp + gb, 60.f)) : 0.f;
            if (kq == 0) {
                gexpL[t & 1][srow] = ex;
                if (trow < segN) attn[seg0 + trow] = ex;   // stash exp(g)
                S += ex;
            }

            // ---- issue next tile (stays in flight across the raw barrier)
            if (t + 1 < nt) {
                const int rr = (t + 1) * 32 + srow;
                const float* xp = x + (size_t)(seg0 + rr) * ND + kq * 8;
                if (rr < segN) { xa = *(const float4*)xp; xb = *(const float4*)(xp + 4); }
                else           { xa = f4z; xb = f4z; }
            }

            asm volatile("s_waitcnt lgkmcnt(0)" ::: "memory");
            __builtin_amdgcn_sched_barrier(0);
            __builtin_amdgcn_s_barrier();        // NO vmcnt drain: T4 pattern

            // ---- compute: 16 rows x 32 cols per wave
            const f32x4 w4 = *(const f32x4*)&gexpL[t & 1][rw * 16 + h * 4];
            f32x4 ac0 = {0.f, 0.f, 0.f, 0.f}, ac1 = {0.f, 0.f, 0.f, 0.f};
            const char* xbase = (const char*)&Xb[t & 1][0];
            const int rowA = rw * 16 + rowl;
            const int sw = (rowA & 7) << 4;
            #pragma unroll
            for (int ks = 0; ks < 8; ++ks) {
                const f16x8 av = *(const f16x8*)(xbase +
                                  (((rowA * 512) + (ks * 64) + (h * 16)) ^ sw));
                ac0 = __builtin_amdgcn_mfma_f32_16x16x32_f16(av, Bf[0][ks], ac0, 0, 0, 0);
                ac1 = __builtin_amdgcn_mfma_f32_16x16x32_f16(av, Bf[1][ks], ac1, 0, 0, 0);
            }
            #pragma unroll
            for (int e = 0; e < 4; ++e) {
                float p0 = ac0[e] + vb0;
                float p1 = ac1[e] + vb1;
                const float we = w4[e];
                z0 += we * p0 * __builtin_amdgcn_rcpf(1.f + __expf(-p0));
                z1 += we * p1 * __builtin_amdgcn_rcpf(1.f + __expf(-p1));
            }
        }

        // ---- graph epilogue ----
        asm volatile("s_waitcnt vmcnt(0)" ::: "memory");   // attn exp stores done

        // prefetch next graph's tile 0 (flies under the whole epilogue)
        const int gn = g + (int)gridDim.x;
        int seg0n = 0, segNn = 0;
        if (gn < ng) {
            seg0n = rs[gn]; segNn = rs[gn + 1] - seg0n;
            if (srow < segNn) {
                const float* xp = x + (size_t)(seg0n + srow) * ND + kq * 8;
                xa = *(const float4*)xp; xb = *(const float4*)(xp + 4);
            } else { xa = f4z; xb = f4z; }
        }

        // h-reduce z; wave-reduce S
        z0 += __shfl_xor(z0, 16, 64); z0 += __shfl_xor(z0, 32, 64);
        z1 += __shfl_xor(z1, 16, 64); z1 += __shfl_xor(z1, 32, 64);
        float Sw = S;
        #pragma unroll
        for (int off = 32; off >= 1; off >>= 1) Sw += __shfl_xor(Sw, off, 64);
        if (lane == 0) sred[wid] = Sw;
        if (rw == 1 && lane < 16) {
            zred[cw * 32 + lane]      = z0;
            zred[cw * 32 + 16 + lane] = z1;
        }
        asm volatile("s_waitcnt lgkmcnt(0)" ::: "memory");
        __builtin_amdgcn_sched_barrier(0);
        __builtin_amdgcn_s_barrier();

        float Stot = 0.f;
        #pragma unroll
        for (int i = 0; i < 16; ++i) Stot += sred[i];
        const float inv = __builtin_amdgcn_rcpf(Stot + 1e-8f);

        if (rw == 0) {
            const float zz0 = z0 + zred[cw * 32 + rowl];
            const float zz1 = z1 + zred[cw * 32 + 16 + rowl];
            if (lane < 16) {
                zout[(size_t)g * OD + cw * 32 + lane]      = zz0 * inv;
                zout[(size_t)g * OD + cw * 32 + 16 + lane] = zz1 * inv;
            }
        }
        for (int i = seg0 + tid; i < seg0 + segN; i += 1024)
            attn[i] *= inv;                      // pure scale (stores drained above)

        __builtin_amdgcn_s_barrier();            // LDS reuse fence for next graph
        g = gn; seg0 = seg0n; segN = segNn;
    }
}

extern "C" void kernel_launch(void* const* d_in, const int* in_sizes, int n_in,
                              void* d_out, int out_size, void* d_ws, size_t ws_size,
                              hipStream_t stream) {
    const float* x       = (const float*)d_in[0];
    const int*   batch   = (const int*)d_in[1];
    const float* gate_w  = (const float*)d_in[3];
    const float* gate_b  = (const float*)d_in[4];
    const float* value_w = (const float*)d_in[5];
    const float* value_b = (const float*)d_in[6];

    const int N  = in_sizes[1];
    const int ng = (out_size - N) / OD;

    int* rs = (int*)d_ws;
    f16* W2 = (f16*)(((uintptr_t)(rs + ng + 1) + 255) & ~(uintptr_t)255);

    k_rowstarts<<<(ng + 1 + 255) / 256, 256, 0, stream>>>(batch, N, ng, rs);
    k_wpack<<<32, 256, 0, stream>>>(value_w, W2);

    float* zout = (float*)d_out;
    float* attn = zout + (size_t)ng * OD;

    const int grid = ng < 256 ? ng : 256;
    k_main<<<grid, 1024, 0, stream>>>(x, rs, gate_w, gate_b, W2, value_b,
                                      zout, attn, ng);
}